// Round 8
// baseline (201.377 us; speedup 1.0000x reference)
//
#include <hip/hip_runtime.h>
#include <hip/hip_bf16.h>

// Problem constants
#define B_   8
#define D1_  1024
#define DJ_  512
#define S_   2048
#define OUT_ 2048
#define IN_  2048          // D1 + 2*DJ
#define M_TOT (B_ * S_)    // 16384

typedef __attribute__((ext_vector_type(8))) short          bf16x8;
typedef __attribute__((ext_vector_type(8))) unsigned short ushort8;
typedef __attribute__((ext_vector_type(4))) float          f32x4;

typedef __attribute__((address_space(3))) unsigned int as3_uint;
typedef __attribute__((address_space(1))) unsigned int as1_uint;

__device__ __forceinline__ unsigned short f2bf(float f) {
    union { float f; unsigned u; } v; v.f = f;
    unsigned r = v.u + 0x7FFF + ((v.u >> 16) & 1);   // round-to-nearest-even
    return (unsigned short)(r >> 16);
}

__device__ __forceinline__ void gload_lds16(const void* g, const void* l) {
    __builtin_amdgcn_global_load_lds(
        (const as1_uint*)(unsigned long long)g,
        (as3_uint*)(unsigned int)(unsigned long long)l,
        16, 0, 0);
}

// ---------------------------------------------------------------------------
// Kernel 1: W f32 -> bf16 (only remaining prep; A-transpose is fused into GEMM)
__global__ __launch_bounds__(256) void convert_w_kernel(
        const float* __restrict__ W, unsigned short* __restrict__ Wb) {
    size_t i = (size_t)blockIdx.x * 256 + threadIdx.x;
    const float4* p = reinterpret_cast<const float4*>(W) + i * 2;
    float4 a = p[0], c = p[1];
    ushort8 h;
    h[0] = f2bf(a.x); h[1] = f2bf(a.y); h[2] = f2bf(a.z); h[3] = f2bf(a.w);
    h[4] = f2bf(c.x); h[5] = f2bf(c.y); h[6] = f2bf(c.z); h[7] = f2bf(c.w);
    *(reinterpret_cast<ushort8*>(Wb) + i) = h;
}

// ---------------------------------------------------------------------------
// Kernel 2: 256x256 bf16 GEMM with FUSED A concat+transpose+convert (round 8).
// C[M,N] = A[M,K] * B[N,K]^T + bias, A read directly from f32 [b][f][s] inputs.
// 512 thr = 8 waves (2M x 4N).  LDS: As/Bs [2 buf][2 region][128][64] = 128 KiB.
// T2 swizzle: 16B k-slot c stored at logical slot c^(lr&7) (both sides).
//
// One superphase per K-tile (64 k), 1 barrier.  Per SP(bb), staging K-tile
// ktn into buf bb^1:
//   A-staging: 32 units block-wide [(s-block, f-slot) = (wave*4+u)]; per unit a
//   thread does 8 coalesced global_load_dword (f-strided rows, s=lane contig),
//   f2bf x8, one swizzled ds_write_b128.  Units pipelined depth-2 (avA/avB)
//   across the 4 quadrant MFMA bursts.
//   B-staging: gload_lds as before (4 loads at SP-top).
//   vmcnt ledger (in-order retirement; queue [u0:8][u1:8][B:4] at SP-top):
//     VMN(12) after q00 -> u0 done (cvt0, issue u2: queue [u1,B,u2])
//     VMN(12) after q01 -> u1 done (cvt1, issue u3: queue [B,u2,u3])
//     VMN(8)  after q11 -> B + u2 done (cvt2)
//     VMN(0)  after q10 -> u3 done (cvt3); lgkm0 (drain ds_writes); barrier.
//   WAR: all stage-writes target buf bb^1, whose last reads ended before the
//   previous SP's barrier.  RAW: B drained at VMN(8)+barrier; A ds_writes at
//   lgkm0+barrier.  Within-SP reads are all from bb, writes all to bb^1.
// A row mapping (matches the old gload region layout, verified g=70,140):
//   g = tile row - m0:  qm=(g>>6)&1,  lr=((g>>7)<<6)|(g&63),  lr&7 == g&7.

__global__ __launch_bounds__(512, 2) void gemm256_kernel(
        const float* __restrict__ in1, const float* __restrict__ in2a,
        const float* __restrict__ in2b,
        const unsigned short* __restrict__ Bm,   // [OUT_][IN_] bf16 (= W)
        const float* __restrict__ bias,
        float* __restrict__ C) {
    __shared__ unsigned short As_[32768];   // [2][2][128][64]
    __shared__ unsigned short Bs_[32768];

    int bid = blockIdx.x;
    // XCD swizzle: nwg = 512 = 8 * 64 (divisible -> simple form bijective)
    int swz = (bid & 7) * 64 + (bid >> 3);
    int m0 = (swz >> 3) * 256;     // 64 mtiles
    int n0 = (swz & 7) * 256;      // 8 ntiles

    int t = threadIdx.x;
    int lane = t & 63, wave = t >> 6;
    int wm = wave >> 2;            // 0..1
    int wn = wave & 3;             // 0..3
    int fr = lane & 15;
    int fkslot = lane >> 4;        // 0..3

    // B staging constants (gload_lds path, pre-swizzled source)
    int sr  = t >> 3;              // 0..63
    int sc  = t & 7;               // 16B slot
    int swc = sc ^ (sr & 7);       // pre-swizzled global k-slot (involution)

    // ds_read swizzled slot offsets (elements) for kk=0,1
    int sl0 = ((fkslot)     ^ (fr & 7)) * 8;
    int sl1 = ((4 + fkslot) ^ (fr & 7)) * 8;
    int arow = wm * 64 + fr;       // A region-local row base
    int brow = wn * 32 + fr;       // B region-local row base

    // A-source decomposition: GEMM row m = b_idx*2048 + s
    int b_idx = m0 >> 11;
    int s0g   = m0 & 2047;         // 256-aligned
    const size_t sb1 = (size_t)b_idx * D1_ * S_;
    const size_t sb2 = (size_t)b_idx * DJ_ * S_;

#define ABASE(ktn_) ((ktn_) < 1024 \
        ? in1 + sb1 + (size_t)(ktn_) * S_ + s0g \
        : ((ktn_) < 1536 \
            ? in2a + sb2 + (size_t)((ktn_) - 1024) * S_ + s0g \
            : in2b + sb2 + (size_t)((ktn_) - 1536) * S_ + s0g))

#define AU_LOAD(REG, u) do { \
    int _idx = wave * 4 + (u); int _fg = _idx & 7; \
    int _so = ((_idx >> 3) << 6) + lane; \
    _Pragma("unroll") \
    for (int _k = 0; _k < 8; ++_k) \
        REG[_k] = ab[(size_t)(_fg * 8 + _k) * S_ + _so]; \
} while (0)

#define AU_CW(REG, u, bbn) do { \
    int _idx = wave * 4 + (u); int _fg = _idx & 7; \
    int _g = ((_idx >> 3) << 6) + lane; \
    int _qm = (_g >> 6) & 1; int _lr = ((_g >> 7) << 6) | (_g & 63); \
    ushort8 _h; \
    _Pragma("unroll") \
    for (int _k = 0; _k < 8; ++_k) _h[_k] = f2bf(REG[_k]); \
    *reinterpret_cast<ushort8*>( \
        As_ + ((bbn)*2 + _qm)*8192 + _lr*64 + (_fg ^ (_lr & 7))*8) = _h; \
} while (0)

#define STAGE_B(bb, h, kt) do { \
    const unsigned short* _g0 = Bm + (size_t)(n0 + (sr>>5)*64 + (h)*32 + (sr&31)) * IN_ + (kt) + swc*8; \
    const unsigned short* _g1 = Bm + (size_t)(n0 + 128 + (sr>>5)*64 + (h)*32 + (sr&31)) * IN_ + (kt) + swc*8; \
    unsigned short* _l = Bs_ + ((bb)*2 + (h))*8192 + sr*64 + sc*8; \
    gload_lds16(_g0, _l); \
    gload_lds16(_g1, _l + 4096); \
} while (0)

#define READ_A(bb, qm) do { \
    const unsigned short* _Ab = As_ + ((bb)*2 + (qm))*8192; \
    _Pragma("unroll") \
    for (int i = 0; i < 4; ++i) { \
        int rr = (arow + i*16) * 64; \
        a_[i][0] = *reinterpret_cast<const bf16x8*>(_Ab + rr + sl0); \
        a_[i][1] = *reinterpret_cast<const bf16x8*>(_Ab + rr + sl1); \
    } \
} while (0)

#define READ_B(bb, qn) do { \
    const unsigned short* _Bb = Bs_ + ((bb)*2 + (qn))*8192; \
    _Pragma("unroll") \
    for (int j = 0; j < 2; ++j) { \
        int rr = (brow + j*16) * 64; \
        b_[j][0] = *reinterpret_cast<const bf16x8*>(_Bb + rr + sl0); \
        b_[j][1] = *reinterpret_cast<const bf16x8*>(_Bb + rr + sl1); \
    } \
} while (0)

#define MFMA4(qm, qn) \
    _Pragma("unroll") \
    for (int i = 0; i < 4; ++i) { \
        _Pragma("unroll") \
        for (int j = 0; j < 2; ++j) { \
            acc[(qm)*4+i][(qn)*2+j] = __builtin_amdgcn_mfma_f32_16x16x32_bf16( \
                a_[i][0], b_[j][0], acc[(qm)*4+i][(qn)*2+j], 0, 0, 0); \
            acc[(qm)*4+i][(qn)*2+j] = __builtin_amdgcn_mfma_f32_16x16x32_bf16( \
                a_[i][1], b_[j][1], acc[(qm)*4+i][(qn)*2+j], 0, 0, 0); \
        } \
    }

#define LGKM0 do { \
    asm volatile("s_waitcnt lgkmcnt(0)" ::: "memory"); \
    __builtin_amdgcn_sched_barrier(0); \
} while (0)

#define VMN(n) do { \
    asm volatile("s_waitcnt vmcnt(" #n ")" ::: "memory"); \
    __builtin_amdgcn_sched_barrier(0); \
} while (0)

#define SP(bb) do { \
    AU_LOAD(avA, 0); \
    AU_LOAD(avB, 1); \
    STAGE_B(bb^1, 0, ktn); \
    STAGE_B(bb^1, 1, ktn); \
    READ_B(bb, 0); READ_A(bb, 0); \
    LGKM0; \
    __builtin_amdgcn_s_setprio(1); \
    MFMA4(0, 0) \
    __builtin_amdgcn_s_setprio(0); \
    VMN(12); \
    AU_CW(avA, 0, bb^1); \
    AU_LOAD(avA, 2); \
    READ_B(bb, 1); \
    LGKM0; \
    __builtin_amdgcn_s_setprio(1); \
    MFMA4(0, 1) \
    __builtin_amdgcn_s_setprio(0); \
    VMN(12); \
    AU_CW(avB, 1, bb^1); \
    AU_LOAD(avB, 3); \
    READ_A(bb, 1); \
    LGKM0; \
    __builtin_amdgcn_s_setprio(1); \
    MFMA4(1, 1) \
    __builtin_amdgcn_s_setprio(0); \
    VMN(8); \
    AU_CW(avA, 2, bb^1); \
    READ_B(bb, 0); \
    LGKM0; \
    __builtin_amdgcn_s_setprio(1); \
    MFMA4(1, 0) \
    __builtin_amdgcn_s_setprio(0); \
    VMN(0); \
    AU_CW(avB, 3, bb^1); \
    asm volatile("s_waitcnt lgkmcnt(0)" ::: "memory"); \
    __builtin_amdgcn_s_barrier(); \
} while (0)

    f32x4 acc[8][4] = {};
    bf16x8 a_[4][2], b_[2][2];
    float avA[8], avB[8];

    // Prologue: stage K-tile 0 into buf0 (A reg-staged, B gload_lds).
    {
        const float* ab = ABASE(0);
        AU_LOAD(avA, 0); AU_LOAD(avB, 1);
        STAGE_B(0, 0, 0); STAGE_B(0, 1, 0);
        VMN(12); AU_CW(avA, 0, 0); AU_LOAD(avA, 2);
        VMN(12); AU_CW(avB, 1, 0); AU_LOAD(avB, 3);
        VMN(8);  AU_CW(avA, 2, 0);
        VMN(0);  AU_CW(avB, 3, 0);
        asm volatile("s_waitcnt lgkmcnt(0)" ::: "memory");
        __builtin_amdgcn_s_barrier();
    }

    // Main loop: SP(0) computes K-tile it*128 (buf0), stages it*128+64 -> buf1;
    //            SP(1) computes it*128+64 (buf1), stages it*128+128 -> buf0.
    // Last stage wraps to 0 (dead; valid addresses, never consumed).
    for (int it = 0; it < IN_ / 128; ++it) {
        int kt1 = it * 128 + 64;
        int kt2 = (it * 128 + 128) & (IN_ - 1);
        { const float* ab = ABASE(kt1); int ktn = kt1; SP(0); }
        { const float* ab = ABASE(kt2); int ktn = kt2; SP(1); }
    }

    // Epilogue: bias + store. C/D layout: col = lane&15, row = (lane>>4)*4 + reg.
    float bv[4];
    #pragma unroll
    for (int n_ = 0; n_ < 4; ++n_) bv[n_] = bias[n0 + wn * 64 + n_ * 16 + fr];
    int crow0 = m0 + wm * 128 + (lane >> 4) * 4;
    int ccol0 = n0 + wn * 64 + fr;
    #pragma unroll
    for (int mi = 0; mi < 8; ++mi) {
        #pragma unroll
        for (int r_ = 0; r_ < 4; ++r_) {
            float* cp = C + (size_t)(crow0 + mi * 16 + r_) * OUT_ + ccol0;
            #pragma unroll
            for (int n_ = 0; n_ < 4; ++n_) cp[n_ * 16] = acc[mi][n_][r_] + bv[n_];
        }
    }
#undef ABASE
#undef AU_LOAD
#undef AU_CW
#undef STAGE_B
#undef READ_A
#undef READ_B
#undef MFMA4
#undef LGKM0
#undef VMN
#undef SP
}

// ---------------------------------------------------------------------------
// Fallback (only if workspace too small): naive fp32, correct but slow.
__global__ __launch_bounds__(256) void naive_kernel(
        const float* __restrict__ in1, const float* __restrict__ in2a,
        const float* __restrict__ in2b, const float* __restrict__ W,
        const float* __restrict__ bias, float* __restrict__ out) {
    size_t id = (size_t)blockIdx.x * 256 + threadIdx.x;
    int s = (int)(id & (S_ - 1));
    size_t bo = id >> 11;
    int o = (int)(bo & (OUT_ - 1));
    int b = (int)(bo >> 11);
    const float* w = W + (size_t)o * IN_;
    float acc = bias[o];
    const float* x1 = in1 + (size_t)b * D1_ * S_ + s;
    for (int f = 0; f < D1_; ++f) acc += x1[(size_t)f * S_] * w[f];
    const float* x2 = in2a + (size_t)b * DJ_ * S_ + s;
    for (int f = 0; f < DJ_; ++f) acc += x2[(size_t)f * S_] * w[D1_ + f];
    const float* x3 = in2b + (size_t)b * DJ_ * S_ + s;
    for (int f = 0; f < DJ_; ++f) acc += x3[(size_t)f * S_] * w[D1_ + DJ_ + f];
    out[((size_t)b * S_ + s) * OUT_ + o] = acc;
}

// ---------------------------------------------------------------------------
extern "C" void kernel_launch(void* const* d_in, const int* in_sizes, int n_in,
                              void* d_out, int out_size, void* d_ws, size_t ws_size,
                              hipStream_t stream) {
    const float* in1  = (const float*)d_in[0];
    const float* in2a = (const float*)d_in[1];
    const float* in2b = (const float*)d_in[2];
    const float* W    = (const float*)d_in[3];
    const float* bias = (const float*)d_in[4];
    float* out = (float*)d_out;

    const size_t wb_bytes = (size_t)OUT_ * IN_ * 2;    // 8,388,608

    if (ws_size < wb_bytes) {
        naive_kernel<<<(B_ * (size_t)OUT_ * S_) / 256, 256, 0, stream>>>(
            in1, in2a, in2b, W, bias, out);
        return;
    }

    unsigned short* Wb = (unsigned short*)d_ws;

    convert_w_kernel<<<(OUT_ * IN_) / (256 * 8), 256, 0, stream>>>(W, Wb);
    gemm256_kernel<<<(M_TOT / 256) * (OUT_ / 256), 512, 0, stream>>>(
        in1, in2a, in2b, Wb, bias, out);
}